// Round 3
// baseline (20.414 us; speedup 1.0000x reference)
//
#include <hip/hip_runtime.h>

// Problem: B=4, C=1024, H=16, D=64.
// Reference broadcasts x along seq -> q/k/v constant over seq -> softmax is
// exactly uniform -> attn@v == v -> out[b] = (x[b] @ Wv + bv) @ Wo + bo.
// Wq/bq/Wk/bk mathematically unused.
//
// Two matvec+bias dispatches. Per leg: 256 blocks x 256 threads; block owns 4
// output columns (float4 of W); threads split K 256-way; wave shfl_xor reduce
// (no barrier) + one cross-wave LDS combine. X (16 KB) read directly from
// global (L1/L2-hot), no LDS staging barrier.

namespace {

constexpr int CD = 1024;  // C
constexpr int BN = 4;     // B

// Y[b][i] = sum_c X[b][c] * W[c][i] + bias[i]
__global__ __launch_bounds__(256)
void matvec_leg(const float* __restrict__ X,    // [4][1024]
                const float* __restrict__ W,    // [1024][1024] ([in][out])
                const float* __restrict__ bias, // [1024]
                float* __restrict__ Y)          // [4][1024]
{
    __shared__ float red[4][16];        // [wave][col*4+b]

    const int tid  = threadIdx.x;
    const int lane = tid & 63;
    const int wv   = tid >> 6;
    const int i0   = blockIdx.x * 4;    // 4 output columns per block

    float a[4][4];                       // [col j][batch b]
#pragma unroll
    for (int j = 0; j < 4; ++j)
#pragma unroll
        for (int b = 0; b < 4; ++b) a[j][b] = 0.f;

    // K split 256-way: c = cc*256 + tid (coalesced across the wave).
#pragma unroll
    for (int cc = 0; cc < CD / 256; ++cc) {
        const int c = cc * 256 + tid;
        const float4 w4 = *(const float4*)(W + (size_t)c * CD + i0);
        float xb[BN];
#pragma unroll
        for (int b = 0; b < BN; ++b) xb[b] = X[b * CD + c];
#pragma unroll
        for (int b = 0; b < BN; ++b) {
            a[0][b] = fmaf(xb[b], w4.x, a[0][b]);
            a[1][b] = fmaf(xb[b], w4.y, a[1][b]);
            a[2][b] = fmaf(xb[b], w4.z, a[2][b]);
            a[3][b] = fmaf(xb[b], w4.w, a[3][b]);
        }
    }

    // Intra-wave butterfly reduce (no barriers).
#pragma unroll
    for (int s = 1; s < 64; s <<= 1) {
#pragma unroll
        for (int j = 0; j < 4; ++j)
#pragma unroll
            for (int b = 0; b < BN; ++b)
                a[j][b] += __shfl_xor(a[j][b], s, 64);
    }

    if (lane == 0) {
#pragma unroll
        for (int j = 0; j < 4; ++j)
#pragma unroll
            for (int b = 0; b < BN; ++b)
                red[wv][j * 4 + b] = a[j][b];
    }
    __syncthreads();

    // 16 finals per block: col j = tid>>2, batch b = tid&3.
    if (tid < 16) {
        const float s = red[0][tid] + red[1][tid] + red[2][tid] + red[3][tid];
        const int j = tid >> 2;
        const int b = tid & 3;
        Y[b * CD + i0 + j] = s + bias[i0 + j];
    }
}

} // namespace

extern "C" void kernel_launch(void* const* d_in, const int* in_sizes, int n_in,
                              void* d_out, int out_size, void* d_ws, size_t ws_size,
                              hipStream_t stream)
{
    // setup_inputs() order: x, Wq, bq, Wk, bk, Wv, bv, Wo, bo  (all fp32)
    const float* x  = (const float*)d_in[0];
    const float* Wv = (const float*)d_in[5];
    const float* bv = (const float*)d_in[6];
    const float* Wo = (const float*)d_in[7];
    const float* bo = (const float*)d_in[8];
    float* out = (float*)d_out;
    float* t   = (float*)d_ws;          // [4][1024] intermediate (16 KB)

    matvec_leg<<<CD / 4, 256, 0, stream>>>(x, Wv, bv, t);
    matvec_leg<<<CD / 4, 256, 0, stream>>>(t, Wo, bo, out);
}